// Round 2
// baseline (10509.666 us; speedup 1.0000x reference)
//
#include <hip/hip_runtime.h>

typedef __bf16 bf16;
typedef __bf16 bf16x8 __attribute__((ext_vector_type(8)));
typedef float f32x4 __attribute__((ext_vector_type(4)));

#define EMBED 768
#define HEADS 12
#define DEPTH 12
#define B_ 256
#define F_ 4
#define L_ 20
#define NTOK 81              // 1 + F_*L_
#define ROWS (B_ * NTOK)     // 20736
#define SROWS (B_ * F_ * L_) // 20480

// ---------------------------------------------------------------------------
// Repack + convert x[..., :2048] (f32, lda=2054) -> contiguous bf16 (20480,2048)
// ---------------------------------------------------------------------------
__global__ __launch_bounds__(256) void repack_kernel(const float* __restrict__ x,
                                                     bf16* __restrict__ xr) {
    int row = blockIdx.x;
    const float* src = x + (size_t)row * 2054;
    bf16* dst = xr + (size_t)row * 2048;
    int t = threadIdx.x;
    int e0 = t * 8;
    bf16 tmp[8];
#pragma unroll
    for (int i = 0; i < 4; ++i) {
        float2 v = *(const float2*)&src[e0 + 2 * i];
        tmp[2 * i] = (bf16)v.x;
        tmp[2 * i + 1] = (bf16)v.y;
    }
    *(uint4*)&dst[e0] = *(const uint4*)tmp;
}

// ---------------------------------------------------------------------------
// GEMM: C[M,N] = A[M,K](bf16) @ W[N,K](f32)^T + bias(f32), fp32 accum.
// W converted f32->bf16 during LDS staging. FUSE: 0 none, 1 exact-gelu,
// 2 add residual R(bf16). ROWMAP: embed row remap. CT: output type.
// Tile 128x128, BK=32, 256 threads (4 waves, 2x2), mfma_f32_16x16x32_bf16.
// ---------------------------------------------------------------------------
template <int FUSE, bool ROWMAP, typename CT>
__global__ __launch_bounds__(256) void gemm_bt(const bf16* __restrict__ A, int lda,
                                               const float* __restrict__ W,
                                               const float* __restrict__ bias,
                                               const bf16* __restrict__ R,
                                               CT* __restrict__ C, int N, int K) {
    __shared__ __align__(16) bf16 As[128][32];
    __shared__ __align__(16) bf16 Ws[128][32];

    const int tid = threadIdx.x;
    const int lane = tid & 63;
    const int wv = tid >> 6;
    const int wm = (wv & 1) * 64;
    const int wn = (wv >> 1) * 64;
    const int lr = lane & 15;
    const int lq = lane >> 4;
    const int m0 = blockIdx.x * 128;
    const int n0 = blockIdx.y * 128;

    f32x4 acc[4][4];
#pragma unroll
    for (int i = 0; i < 4; ++i)
#pragma unroll
        for (int j = 0; j < 4; ++j) acc[i][j] = (f32x4){0.f, 0.f, 0.f, 0.f};

    for (int k0 = 0; k0 < K; k0 += 32) {
        // A: bf16, 512 chunks of 8 elements (16B)
#pragma unroll
        for (int i = 0; i < 2; ++i) {
            int c = tid + 256 * i;
            int row = c >> 2;
            int kc = (c & 3) * 8;
            *(uint4*)&As[row][kc] = *(const uint4*)&A[(size_t)(m0 + row) * lda + k0 + kc];
        }
        // W: f32, 1024 chunks of 4 floats (16B), convert to bf16
#pragma unroll
        for (int i = 0; i < 4; ++i) {
            int c = tid + 256 * i;
            int row = c >> 3;
            int kc = (c & 7) * 4;
            float4 v = *(const float4*)&W[(size_t)(n0 + row) * K + k0 + kc];
            bf16 wb[4] = {(bf16)v.x, (bf16)v.y, (bf16)v.z, (bf16)v.w};
            *(uint2*)&Ws[row][kc] = *(const uint2*)wb;
        }
        __syncthreads();
        bf16x8 af[4], bf_[4];
#pragma unroll
        for (int t = 0; t < 4; ++t) {
            af[t] = *(const bf16x8*)&As[wm + t * 16 + lr][lq * 8];
            bf_[t] = *(const bf16x8*)&Ws[wn + t * 16 + lr][lq * 8];
        }
#pragma unroll
        for (int mi = 0; mi < 4; ++mi)
#pragma unroll
            for (int ni = 0; ni < 4; ++ni)
                acc[mi][ni] = __builtin_amdgcn_mfma_f32_16x16x32_bf16(af[mi], bf_[ni],
                                                                      acc[mi][ni], 0, 0, 0);
        __syncthreads();
    }

#pragma unroll
    for (int mi = 0; mi < 4; ++mi) {
#pragma unroll
        for (int ni = 0; ni < 4; ++ni) {
            int gcol = n0 + wn + ni * 16 + lr;
            float bv = bias ? bias[gcol] : 0.f;
#pragma unroll
            for (int r = 0; r < 4; ++r) {
                int grow = m0 + wm + mi * 16 + lq * 4 + r;
                float v = acc[mi][ni][r] + bv;
                if (FUSE == 1) v = 0.5f * v * (1.f + erff(v * 0.70710678118654752f));
                if (FUSE == 2) v += (float)R[(size_t)grow * N + gcol];
                int orow = grow;
                if (ROWMAP) orow = grow + grow / 80 + 1;  // skip cls rows
                C[(size_t)orow * N + gcol] = (CT)v;
            }
        }
    }
}

// ---------------------------------------------------------------------------
// Embed finish: add pos (K=6, f32) + pos_b + temporal_embed into tok (bf16)
// ---------------------------------------------------------------------------
__global__ __launch_bounds__(256) void embed_finish(const float* __restrict__ x,
                                                    const float* __restrict__ posW,
                                                    const float* __restrict__ posb,
                                                    const float* __restrict__ temb,
                                                    bf16* __restrict__ tok) {
    int r = blockIdx.x;  // 0..20479
    int fr = (r % 80) / 20;
    int orow = r + r / 80 + 1;
    __shared__ float pf[6];
    if (threadIdx.x < 6) pf[threadIdx.x] = x[(size_t)r * 2054 + 2048 + threadIdx.x];
    __syncthreads();
    int t = threadIdx.x;
#pragma unroll
    for (int i = 0; i < 3; ++i) {
        int c = t + 256 * i;
        float v = posb[c] + temb[fr * EMBED + c];
#pragma unroll
        for (int j = 0; j < 6; ++j) v += pf[j] * posW[c * 6 + j];
        size_t idx = (size_t)orow * EMBED + c;
        tok[idx] = (bf16)((float)tok[idx] + v);
    }
}

// ---------------------------------------------------------------------------
// cls rows (bf16 tok) + mbias (f32 scratch) + output 1 (f32)
// ---------------------------------------------------------------------------
__global__ __launch_bounds__(256) void cls_mbias_kernel(const float* __restrict__ cls_tok,
                                                        const float* __restrict__ cls_pos,
                                                        const int* __restrict__ xmask,
                                                        bf16* __restrict__ tok,
                                                        float* __restrict__ mbias,
                                                        float* __restrict__ out1) {
    int b = blockIdx.x;
    int t = threadIdx.x;
#pragma unroll
    for (int i = 0; i < 3; ++i) {
        int c = t + 256 * i;
        tok[(size_t)(b * NTOK) * EMBED + c] = (bf16)(cls_tok[c] + cls_pos[c]);
    }
    if (t < NTOK) {
        float mv = (t == 0) ? 0.f : ((float)xmask[b * 80 + t - 1] - 1.f) * 100.f;
        mbias[b * NTOK + t] = mv;
        out1[b * NTOK + t] = mv;
    }
}

// ---------------------------------------------------------------------------
// LayerNorm: one block per row, 768 cols, fp32 stats, eps=1e-6. w/b f32.
// ---------------------------------------------------------------------------
__global__ __launch_bounds__(256) void ln_kernel(const bf16* __restrict__ X,
                                                 const float* __restrict__ w,
                                                 const float* __restrict__ b,
                                                 bf16* __restrict__ Y) {
    int row = blockIdx.x;
    const bf16* xr = X + (size_t)row * EMBED;
    int t = threadIdx.x;
    float xv[3], s = 0.f, ss = 0.f;
#pragma unroll
    for (int i = 0; i < 3; ++i) {
        float v = (float)xr[t + 256 * i];
        xv[i] = v;
        s += v;
        ss += v * v;
    }
#pragma unroll
    for (int off = 32; off; off >>= 1) {
        s += __shfl_down(s, off);
        ss += __shfl_down(ss, off);
    }
    __shared__ float ws_s[4], ws_q[4];
    int wv = t >> 6, lane = t & 63;
    if (lane == 0) { ws_s[wv] = s; ws_q[wv] = ss; }
    __syncthreads();
    s = ws_s[0] + ws_s[1] + ws_s[2] + ws_s[3];
    ss = ws_q[0] + ws_q[1] + ws_q[2] + ws_q[3];
    float mean = s * (1.f / 768.f);
    float var = ss * (1.f / 768.f) - mean * mean;
    float inv = rsqrtf(fmaxf(var, 0.f) + 1e-6f);
#pragma unroll
    for (int i = 0; i < 3; ++i) {
        int c = t + 256 * i;
        Y[(size_t)row * EMBED + c] = (bf16)((xv[i] - mean) * inv * w[c] + b[c]);
    }
}

// ---------------------------------------------------------------------------
// Frame-local attention. One block per (batch, head). N=81, d=64, f=4, n=20.
// cls attends to all 81; spatial token attends to {cls} ∪ frame (21 keys).
// ---------------------------------------------------------------------------
__global__ __launch_bounds__(256) void attn_kernel(const bf16* __restrict__ qkv,
                                                   const float* __restrict__ mbias,
                                                   bf16* __restrict__ aout) {
    int bh = blockIdx.x;
    int b = bh / HEADS, h = bh % HEADS;
    __shared__ bf16 Qs[NTOK][66], Ks[NTOK][66], Vs[NTOK][66];
    __shared__ float S[80][21];
    __shared__ float Sc[NTOK];
    __shared__ float MB[NTOK];
    const size_t base = (size_t)(b * NTOK) * 2304 + h * 64;
    int t = threadIdx.x;
    for (int e = t; e < NTOK * 64; e += 256) {
        int r = e >> 6, c = e & 63;
        size_t o = base + (size_t)r * 2304 + c;
        Qs[r][c] = (bf16)((float)qkv[o] * 0.125f);
        Ks[r][c] = qkv[o + 768];
        Vs[r][c] = qkv[o + 1536];
    }
    if (t < NTOK) MB[t] = mbias[b * NTOK + t];
    __syncthreads();
    for (int j = t; j < 80 * 21 + NTOK; j += 256) {
        if (j < 1680) {
            int qi = j / 21, kj = j % 21;
            int qt = 1 + qi;
            int kt = (kj == 0) ? 0 : (qi / 20) * 20 + kj;
            float sv = 0.f;
            for (int c = 0; c < 64; ++c) sv += (float)Qs[qt][c] * (float)Ks[kt][c];
            S[qi][kj] = sv + MB[kt];
        } else {
            int kt = j - 1680;
            float sv = 0.f;
            for (int c = 0; c < 64; ++c) sv += (float)Qs[0][c] * (float)Ks[kt][c];
            Sc[kt] = sv + MB[kt];
        }
    }
    __syncthreads();
    if (t < 80) {
        float mx = -1e30f;
        for (int j = 0; j < 21; ++j) mx = fmaxf(mx, S[t][j]);
        float sum = 0.f;
        for (int j = 0; j < 21; ++j) { float e = __expf(S[t][j] - mx); S[t][j] = e; sum += e; }
        float rs = 1.f / sum;
        for (int j = 0; j < 21; ++j) S[t][j] *= rs;
    } else if (t == 80) {
        float mx = -1e30f;
        for (int j = 0; j < NTOK; ++j) mx = fmaxf(mx, Sc[j]);
        float sum = 0.f;
        for (int j = 0; j < NTOK; ++j) { float e = __expf(Sc[j] - mx); Sc[j] = e; sum += e; }
        float rs = 1.f / sum;
        for (int j = 0; j < NTOK; ++j) Sc[j] *= rs;
    }
    __syncthreads();
    for (int e = t; e < NTOK * 64; e += 256) {
        int r = e >> 6, c = e & 63;
        float o = 0.f;
        if (r == 0) {
            for (int j = 0; j < NTOK; ++j) o += Sc[j] * (float)Vs[j][c];
        } else {
            int qi = r - 1, fb = (qi / 20) * 20;
            o += S[qi][0] * (float)Vs[0][c];
            for (int j = 1; j < 21; ++j) o += S[qi][j] * (float)Vs[fb + j][c];
        }
        aout[(size_t)(b * NTOK + r) * EMBED + h * 64 + c] = (bf16)o;
    }
}

// ---------------------------------------------------------------------------
extern "C" void kernel_launch(void* const* d_in, const int* in_sizes, int n_in,
                              void* d_out, int out_size, void* d_ws, size_t ws_size,
                              hipStream_t stream) {
    const float* x = (const float*)d_in[0];
    const int* xmask = (const int*)d_in[1];
    const float* objW = (const float*)d_in[2];
    const float* objb = (const float*)d_in[3];
    const float* posW = (const float*)d_in[4];
    const float* posb = (const float*)d_in[5];
    const float* clsT = (const float*)d_in[6];
    const float* clsP = (const float*)d_in[7];
    const float* temb = (const float*)d_in[8];
    const float* ln1w = (const float*)d_in[9];
    const float* ln1b = (const float*)d_in[10];
    const float* ln2w = (const float*)d_in[11];
    const float* ln2b = (const float*)d_in[12];
    const float* qkvW = (const float*)d_in[13];
    const float* qkvb = (const float*)d_in[14];
    const float* apW = (const float*)d_in[15];
    const float* apb = (const float*)d_in[16];
    const float* f1W = (const float*)d_in[17];
    const float* f1b = (const float*)d_in[18];
    const float* f2W = (const float*)d_in[19];
    const float* f2b = (const float*)d_in[20];
    const float* projW = (const float*)d_in[21];

    char* ws = (char*)d_ws;
    bf16* tok = (bf16*)(ws);                              // 30.4 MiB
    bf16* s1 = (bf16*)(ws + (size_t)(32 << 20));          // 30.4 MiB (ln out / attn out)
    float* mb = (float*)(ws + (size_t)(64 << 20));        // 83 KB
    bf16* big = (bf16*)(ws + (size_t)(65 << 20));         // up to 121.5 MiB (xr/qkv/hidden)
    float* out0 = (float*)d_out;
    float* out1 = out0 + (size_t)ROWS * 256;

    // Embedding
    repack_kernel<<<SROWS, 256, 0, stream>>>(x, big);
    gemm_bt<0, true, bf16><<<dim3(SROWS / 128, EMBED / 128), 256, 0, stream>>>(
        big, 2048, objW, objb, nullptr, tok, EMBED, 2048);
    embed_finish<<<SROWS, 256, 0, stream>>>(x, posW, posb, temb, tok);
    cls_mbias_kernel<<<B_, 256, 0, stream>>>(clsT, clsP, xmask, tok, mb, out1);

    // Transformer layers
    for (int l = 0; l < DEPTH; ++l) {
        ln_kernel<<<ROWS, 256, 0, stream>>>(tok, ln1w + l * EMBED, ln1b + l * EMBED, s1);
        gemm_bt<0, false, bf16><<<dim3(ROWS / 128, 2304 / 128), 256, 0, stream>>>(
            s1, EMBED, qkvW + (size_t)l * 2304 * EMBED, qkvb + l * 2304, nullptr, big, 2304, EMBED);
        attn_kernel<<<B_ * HEADS, 256, 0, stream>>>(big, mb, s1);
        gemm_bt<2, false, bf16><<<dim3(ROWS / 128, EMBED / 128), 256, 0, stream>>>(
            s1, EMBED, apW + (size_t)l * EMBED * EMBED, apb + l * EMBED, tok, tok, EMBED, EMBED);
        ln_kernel<<<ROWS, 256, 0, stream>>>(tok, ln2w + l * EMBED, ln2b + l * EMBED, s1);
        gemm_bt<1, false, bf16><<<dim3(ROWS / 128, 3072 / 128), 256, 0, stream>>>(
            s1, EMBED, f1W + (size_t)l * 3072 * EMBED, f1b + l * 3072, nullptr, big, 3072, EMBED);
        gemm_bt<2, false, bf16><<<dim3(ROWS / 128, EMBED / 128), 256, 0, stream>>>(
            big, 3072, f2W + (size_t)l * EMBED * 3072, f2b + l * EMBED, tok, tok, EMBED, 3072);
    }

    // Final projection (no bias), f32 output
    gemm_bt<0, false, float><<<dim3(ROWS / 128, 256 / 128), 256, 0, stream>>>(
        tok, EMBED, projW, nullptr, nullptr, out0, 256, EMBED);
}